// Round 2
// baseline (620.806 us; speedup 1.0000x reference)
//
#include <hip/hip_runtime.h>
#include <hip/hip_bf16.h>

// messages = relu(concat(node[src], node[tgt], edge) @ W + b) -> segment_sum by tgt
// R2 strategy: device counting-sort edges by tgt; MFMA gather-GEMM writes bf16
// messages in tgt-sorted order (coalesced); per-node wave pools contiguous runs.
// No scattered atomics on the hot path.

using s16x8 = __attribute__((ext_vector_type(8))) short;
using f32x4 = __attribute__((ext_vector_type(4))) float;

static __device__ __forceinline__ ushort f2bf(float f) {
    union { __hip_bfloat16 h; ushort u; } cv;
    cv.h = __float2bfloat16(f);
    return cv.u;
}
static __device__ __forceinline__ float bf2f(ushort u) {
    union { unsigned u; float f; } cv;
    cv.u = ((unsigned)u) << 16;
    return cv.f;
}

// ---- Transpose + convert W[192][64] f32 -> WT[64][192] bf16 ----
__global__ void prep_wt(const float* __restrict__ W, ushort* __restrict__ WT) {
    int idx = blockIdx.x * blockDim.x + threadIdx.x;   // idx = n*192 + k
    if (idx < 64 * 192) {
        int n = idx / 192;
        int k = idx % 192;
        WT[idx] = f2bf(W[k * 64 + n]);
    }
}

// ---- Counting sort: histogram over targets ----
__global__ void hist_tgt(const int* __restrict__ tgt, int* __restrict__ counts, int n_edges) {
    int i = blockIdx.x * blockDim.x + threadIdx.x;
    if (i < n_edges) atomicAdd(&counts[tgt[i]], 1);
}

// ---- Exclusive scan of counts (single block, wave-shuffle scan) ----
__global__ __launch_bounds__(1024) void scan_counts(
    const int* __restrict__ counts, int* __restrict__ offsets, int* __restrict__ woff,
    int n_nodes, int n_edges)
{
    __shared__ int wsum[16];
    __shared__ int base_s;
    const int tid = threadIdx.x, lane = tid & 63, wid = tid >> 6;
    if (tid == 0) base_s = 0;
    __syncthreads();
    for (int c0 = 0; c0 < n_nodes; c0 += 1024) {
        const int idx = c0 + tid;
        const int v = (idx < n_nodes) ? counts[idx] : 0;
        int x = v;
#pragma unroll
        for (int o = 1; o < 64; o <<= 1) { int t = __shfl_up(x, o, 64); if (lane >= o) x += t; }
        if (lane == 63) wsum[wid] = x;
        __syncthreads();
        if (tid < 16) {
            int w = wsum[tid];
#pragma unroll
            for (int o = 1; o < 16; o <<= 1) { int t = __shfl_up(w, o, 16); if (tid >= o) w += t; }
            wsum[tid] = w;
        }
        __syncthreads();
        const int wbase = (wid == 0) ? 0 : wsum[wid - 1];
        const int excl = base_s + wbase + x - v;   // base_s: stable since prev iter's sync
        if (idx < n_nodes) { offsets[idx] = excl; woff[idx] = excl; }
        const int total = wsum[15];
        __syncthreads();
        if (tid == 0) base_s += total;
        __syncthreads();
    }
    if (threadIdx.x == 0) offsets[n_nodes] = n_edges;
}

// ---- Scatter edge ids into tgt-sorted order ----
__global__ void build_perm(const int* __restrict__ tgt, int* __restrict__ woff,
                           int* __restrict__ perm, int n_edges) {
    int i = blockIdx.x * blockDim.x + threadIdx.x;
    if (i < n_edges) {
        int p = atomicAdd(&woff[tgt[i]], 1);
        perm[p] = i;
    }
}

// ---- MFMA gather-GEMM over sorted edges; writes bf16 messages contiguously ----
__global__ __launch_bounds__(256) void edge_gemm_sorted(
    const float* __restrict__ node, const float* __restrict__ edgef,
    const int* __restrict__ src, const int* __restrict__ tgt,
    const int* __restrict__ perm,
    const ushort* __restrict__ WT, const float* __restrict__ bias,
    ushort* __restrict__ msg, int n_edges)
{
    // Per-wave A tile: 16 edges x 192 K bf16, padded 192->200 (bank-conflict G4).
    __shared__ __align__(16) ushort A[4][16][200];

    const int wave = threadIdx.x >> 6;
    const int lane = threadIdx.x & 63;
    const int g = lane >> 4;   // k-group 0..3
    const int r = lane & 15;   // row/col within fragment

    // B fragments: lane holds WT[nt*16+r][ks*32+g*8 .. +8)
    s16x8 Bf[4][6];
#pragma unroll
    for (int nt = 0; nt < 4; ++nt)
#pragma unroll
        for (int ks = 0; ks < 6; ++ks)
            Bf[nt][ks] = *reinterpret_cast<const s16x8*>(WT + (nt * 16 + r) * 192 + ks * 32 + g * 8);

    float bv[4];
#pragma unroll
    for (int nt = 0; nt < 4; ++nt) bv[nt] = bias[nt * 16 + r];

    const int tile0 = blockIdx.x * 64 + wave * 16;   // first sorted position of this tile

    // Resolve permuted edge ids once (4 local rows per lane: el = i*4+g)
    int eidx[4], sidx[4], tidx[4];
#pragma unroll
    for (int i = 0; i < 4; ++i) {
        int pos = tile0 + i * 4 + g;
        if (pos >= n_edges) pos = n_edges - 1;
        eidx[i] = perm[pos];
    }
#pragma unroll
    for (int i = 0; i < 4; ++i) { sidx[i] = src[eidx[i]]; tidx[i] = tgt[eidx[i]]; }

    // ---- Stage A: gather rows, cvt f32->bf16, write LDS ----
#pragma unroll
    for (int seg = 0; seg < 3; ++seg) {
#pragma unroll
        for (int i = 0; i < 4; ++i) {
            const int el = i * 4 + g;
            const float* p;
            if (seg == 0)      p = node + (size_t)sidx[i] * 64;
            else if (seg == 1) p = node + (size_t)tidx[i] * 64;
            else               p = edgef + (size_t)eidx[i] * 64;
            const f32x4 v = *reinterpret_cast<const f32x4*>(p + r * 4);
            ushort4 h;
            h.x = f2bf(v[0]); h.y = f2bf(v[1]); h.z = f2bf(v[2]); h.w = f2bf(v[3]);
            *reinterpret_cast<ushort4*>(&A[wave][el][seg * 64 + r * 4]) = h;
        }
    }
    __syncthreads();

    // ---- MFMA: 6 k-steps x 4 n-tiles ----
    f32x4 acc[4] = {{0.f,0.f,0.f,0.f},{0.f,0.f,0.f,0.f},{0.f,0.f,0.f,0.f},{0.f,0.f,0.f,0.f}};
#pragma unroll
    for (int ks = 0; ks < 6; ++ks) {
        const s16x8 a = *reinterpret_cast<const s16x8*>(&A[wave][r][ks * 32 + g * 8]);
#pragma unroll
        for (int nt = 0; nt < 4; ++nt)
            acc[nt] = __builtin_amdgcn_mfma_f32_16x16x32_bf16(a, Bf[nt][ks], acc[nt], 0, 0, 0);
    }

    // ---- Epilogue: relu(acc+b) -> LDS transpose -> coalesced bf16 global store ----
    // C/D layout: col = lane&15 (n within tile), row = (lane>>4)*4 + j
    __syncthreads();   // A staging fully consumed by all waves before reuse
#pragma unroll
    for (int nt = 0; nt < 4; ++nt) {
#pragma unroll
        for (int j = 0; j < 4; ++j) {
            const int row = g * 4 + j;
            const float v = fmaxf(acc[nt][j] + bv[nt], 0.0f);
            A[wave][row][nt * 16 + r] = f2bf(v);
        }
    }
    __syncthreads();
    const int row = lane >> 2, q = lane & 3;
    if (tile0 + row < n_edges) {
        const s16x8 m0 = *reinterpret_cast<const s16x8*>(&A[wave][row][q * 16]);
        const s16x8 m1 = *reinterpret_cast<const s16x8*>(&A[wave][row][q * 16 + 8]);
        const size_t p = (size_t)(tile0 + row) * 64 + q * 16;
        *reinterpret_cast<s16x8*>(msg + p) = m0;
        *reinterpret_cast<s16x8*>(msg + p + 8) = m1;
    }
}

// ---- Per-node pooling of contiguous sorted message runs ----
__global__ __launch_bounds__(256) void pool_msgs(
    const ushort* __restrict__ msg, const int* __restrict__ offsets,
    float* __restrict__ out, int n_nodes)
{
    const int wave = threadIdx.x >> 6, lane = threadIdx.x & 63;
    const int n = blockIdx.x * 4 + wave;
    if (n >= n_nodes) return;
    const int s = offsets[n], e = offsets[n + 1];
    float acc = 0.f;
    for (int i = s; i < e; ++i) acc += bf2f(msg[(size_t)i * 64 + lane]);
    out[(size_t)n * 64 + lane] = acc;
}

// ---- Fallback (R1 path): atomic scatter, used only if ws too small ----
__global__ __launch_bounds__(256) void edge_gemm_atomic(
    const float* __restrict__ node, const float* __restrict__ edgef,
    const int* __restrict__ src, const int* __restrict__ tgt,
    const ushort* __restrict__ WT, const float* __restrict__ bias,
    float* __restrict__ out, int n_edges)
{
    __shared__ __align__(16) ushort A[4][16][200];
    const int wave = threadIdx.x >> 6;
    const int lane = threadIdx.x & 63;
    const int g = lane >> 4, r = lane & 15;
    s16x8 Bf[4][6];
#pragma unroll
    for (int nt = 0; nt < 4; ++nt)
#pragma unroll
        for (int ks = 0; ks < 6; ++ks)
            Bf[nt][ks] = *reinterpret_cast<const s16x8*>(WT + (nt * 16 + r) * 192 + ks * 32 + g * 8);
    float bv[4];
#pragma unroll
    for (int nt = 0; nt < 4; ++nt) bv[nt] = bias[nt * 16 + r];
    const int tile0 = blockIdx.x * 64 + wave * 16;
#pragma unroll
    for (int seg = 0; seg < 3; ++seg) {
#pragma unroll
        for (int i = 0; i < 4; ++i) {
            const int el = i * 4 + g;
            const int e = tile0 + el;
            const int ee = (e < n_edges) ? e : 0;
            const float* p;
            if (seg == 0)      p = node + (size_t)src[ee] * 64;
            else if (seg == 1) p = node + (size_t)tgt[ee] * 64;
            else               p = edgef + (size_t)ee * 64;
            const f32x4 v = *reinterpret_cast<const f32x4*>(p + r * 4);
            ushort4 h;
            h.x = f2bf(v[0]); h.y = f2bf(v[1]); h.z = f2bf(v[2]); h.w = f2bf(v[3]);
            *reinterpret_cast<ushort4*>(&A[wave][el][seg * 64 + r * 4]) = h;
        }
    }
    __syncthreads();
    f32x4 acc[4] = {{0.f,0.f,0.f,0.f},{0.f,0.f,0.f,0.f},{0.f,0.f,0.f,0.f},{0.f,0.f,0.f,0.f}};
#pragma unroll
    for (int ks = 0; ks < 6; ++ks) {
        const s16x8 a = *reinterpret_cast<const s16x8*>(&A[wave][r][ks * 32 + g * 8]);
#pragma unroll
        for (int nt = 0; nt < 4; ++nt)
            acc[nt] = __builtin_amdgcn_mfma_f32_16x16x32_bf16(a, Bf[nt][ks], acc[nt], 0, 0, 0);
    }
#pragma unroll
    for (int nt = 0; nt < 4; ++nt) {
        const int n = nt * 16 + r;
#pragma unroll
        for (int j = 0; j < 4; ++j) {
            const int row = g * 4 + j;
            const int e = tile0 + row;
            if (e < n_edges) {
                float v = fmaxf(acc[nt][j] + bv[nt], 0.0f);
                unsafeAtomicAdd(out + (size_t)tgt[e] * 64 + n, v);
            }
        }
    }
}

extern "C" void kernel_launch(void* const* d_in, const int* in_sizes, int n_in,
                              void* d_out, int out_size, void* d_ws, size_t ws_size,
                              hipStream_t stream) {
    const float* node  = (const float*)d_in[0];
    const float* edgef = (const float*)d_in[1];
    const int*   src   = (const int*)d_in[2];
    const int*   tgt   = (const int*)d_in[3];
    const float* W     = (const float*)d_in[4];
    const float* bias  = (const float*)d_in[5];
    float* out = (float*)d_out;
    const int n_edges = in_sizes[2];
    const int n_nodes = in_sizes[0] / 64;

    // Workspace layout (256B-aligned chunks)
    char* ws = (char*)d_ws;
    size_t cur = 0;
    auto take = [&](size_t b) { size_t s = cur; cur = (cur + b + 255) & ~(size_t)255; return s; };
    const size_t oWT   = take((size_t)64 * 192 * 2);
    const size_t oCnt  = take((size_t)n_nodes * 4);
    const size_t oOff  = take((size_t)(n_nodes + 1) * 4);
    const size_t oWoff = take((size_t)n_nodes * 4);
    const size_t oPerm = take((size_t)n_edges * 4);
    const size_t oMsg  = take((size_t)n_edges * 64 * 2);
    const bool sorted_ok = (cur <= ws_size);

    ushort* WT = (ushort*)(ws + oWT);
    prep_wt<<<48, 256, 0, stream>>>(W, WT);

    if (sorted_ok) {
        int* counts  = (int*)(ws + oCnt);
        int* offsets = (int*)(ws + oOff);
        int* woff    = (int*)(ws + oWoff);
        int* perm    = (int*)(ws + oPerm);
        ushort* msg  = (ushort*)(ws + oMsg);

        hipMemsetAsync(counts, 0, (size_t)n_nodes * 4, stream);
        hist_tgt<<<(n_edges + 255) / 256, 256, 0, stream>>>(tgt, counts, n_edges);
        scan_counts<<<1, 1024, 0, stream>>>(counts, offsets, woff, n_nodes, n_edges);
        build_perm<<<(n_edges + 255) / 256, 256, 0, stream>>>(tgt, woff, perm, n_edges);
        edge_gemm_sorted<<<(n_edges + 63) / 64, 256, 0, stream>>>(
            node, edgef, src, tgt, perm, WT, bias, msg, n_edges);
        pool_msgs<<<(n_nodes + 3) / 4, 256, 0, stream>>>(msg, offsets, out, n_nodes);
    } else {
        hipMemsetAsync(d_out, 0, (size_t)out_size * sizeof(float), stream);
        edge_gemm_atomic<<<(n_edges + 63) / 64, 256, 0, stream>>>(
            node, edgef, src, tgt, WT, bias, out, n_edges);
    }
}